// Round 1
// baseline (287.936 us; speedup 1.0000x reference)
//
#include <hip/hip_runtime.h>

#define TPB 256
#define QPT 4  // quads (of 4 edges) per thread

__global__ __launch_bounds__(TPB) void zbl_kernel(
    const float* __restrict__ rij,
    const float* __restrict__ rcov,
    const float* __restrict__ znum,
    const int*  __restrict__ fa,
    const int*  __restrict__ sa,
    const int*  __restrict__ types,
    float* __restrict__ out,
    int E, int nquad)
{
    // 16-entry (ti,tj) table, SoA layout: field f, entry t at tab[f][t].
    // Bank = (f*16 + t) % 32 -> each field's 16 entries occupy 16 distinct
    // banks -> conflict-free random-entry reads.
    __shared__ float tab[9][16];
    if (threadIdx.x < 16) {
        const float cc[4] = {0.02817f, 0.28022f, 0.50986f, 0.18175f};
        const float dd[4] = {0.20162f, 0.4029f, 0.94229f, 3.1998f};
        const float COUL = 14.399645478425668f;
        int t = threadIdx.x;
        int ti = t >> 2, tj = t & 3;
        float zi = znum[ti], zj = znum[tj];
        float rc = rcov[ti] + rcov[tj];
        float a = 0.4685f / (powf(zi, 0.23f) + powf(zj, 0.23f));
        float inva = 1.0f / a;
        float factor = COUL * zi * zj;
        float da[4], ee[4];
        float phi = 0.0f, dphi = 0.0f, d2phi = 0.0f;
        #pragma unroll
        for (int k = 0; k < 4; ++k) {
            da[k] = dd[k] * inva;
            ee[k] = expf(-rc * da[k]);
            phi   += cc[k] * ee[k];
            dphi  -= cc[k] * da[k] * ee[k];
            d2phi += cc[k] * da[k] * da[k] * ee[k];
        }
        float invrc = 1.0f / rc;
        float ec   = factor * invrc * phi;
        float dec  = factor * invrc * (-phi * invrc + dphi);
        float d2ec = factor * invrc * (d2phi - 2.0f * invrc * dphi + 2.0f * phi * invrc * invrc);
        float A = (-3.0f * dec + rc * d2ec) * invrc * invrc;
        float B = (2.0f * dec - rc * d2ec) * invrc * invrc * invrc;
        float C = -ec + 0.5f * rc * dec - rc * rc * d2ec * (1.0f / 12.0f);
        const float L2E = 1.4426950408889634f;
        tab[0][t] = 0.5f * factor;      // folds the final e/2
        tab[1][t] = rc;
        tab[2][t] = -da[0] * L2E;       // exp(-r*da) = exp2(r * (-da*log2e))
        tab[3][t] = -da[1] * L2E;
        tab[4][t] = -da[2] * L2E;
        tab[5][t] = -da[3] * L2E;
        tab[6][t] = A * (1.0f / 6.0f);  // A/3 * 1/2
        tab[7][t] = B * 0.125f;         // B/4 * 1/2
        tab[8][t] = C * 0.5f;
    }
    __syncthreads();

    const float cc0 = 0.02817f, cc1 = 0.28022f, cc2 = 0.50986f, cc3 = 0.18175f;
    const float4* rij4 = (const float4*)rij;
    const int4*   fa4  = (const int4*)fa;
    const int4*   sa4  = (const int4*)sa;

    int tid = blockIdx.x * TPB + threadIdx.x;
    int nth = gridDim.x * TPB;

    for (int q = tid; q < nquad; q += nth) {
        float4 rv = rij4[q];
        int4   iv = fa4[q];
        int4   jv = sa4[q];
        float ra[4] = {rv.x, rv.y, rv.z, rv.w};
        int   ia[4] = {iv.x, iv.y, iv.z, iv.w};
        int   ja[4] = {jv.x, jv.y, jv.z, jv.w};
        int   ta[4];
        #pragma unroll
        for (int k = 0; k < 4; ++k)
            ta[k] = types[ia[k]] * 4 + types[ja[k]];  // both gathers issue early
        #pragma unroll
        for (int k = 0; k < 4; ++k) {
            int t = ta[k];
            float r = ra[k];
            float rc = tab[1][t];
            if (r <= rc) {
                float p = cc0 * __builtin_amdgcn_exp2f(r * tab[2][t])
                        + cc1 * __builtin_amdgcn_exp2f(r * tab[3][t])
                        + cc2 * __builtin_amdgcn_exp2f(r * tab[4][t])
                        + cc3 * __builtin_amdgcn_exp2f(r * tab[5][t]);
                float r2 = r * r;
                float r3 = r2 * r;
                float poly = __builtin_fmaf(__builtin_fmaf(tab[7][t], r, tab[6][t]), r3, tab[8][t]);
                float e = __builtin_fmaf(tab[0][t] * p, __builtin_amdgcn_rcpf(r), poly);
                unsafeAtomicAdd(&out[ia[k]], e);  // HW global_atomic_add_f32
            }
        }
    }

    // tail (E not divisible by 4)
    int base = nquad * 4;
    for (int idx = base + tid; idx < E; idx += nth) {
        int i = fa[idx], j = sa[idx];
        int t = types[i] * 4 + types[j];
        float r = rij[idx];
        float rc = tab[1][t];
        if (r <= rc) {
            float p = cc0 * __builtin_amdgcn_exp2f(r * tab[2][t])
                    + cc1 * __builtin_amdgcn_exp2f(r * tab[3][t])
                    + cc2 * __builtin_amdgcn_exp2f(r * tab[4][t])
                    + cc3 * __builtin_amdgcn_exp2f(r * tab[5][t]);
            float r2 = r * r;
            float r3 = r2 * r;
            float poly = __builtin_fmaf(__builtin_fmaf(tab[7][t], r, tab[6][t]), r3, tab[8][t]);
            float e = __builtin_fmaf(tab[0][t] * p, __builtin_amdgcn_rcpf(r), poly);
            unsafeAtomicAdd(&out[i], e);
        }
    }
}

extern "C" void kernel_launch(void* const* d_in, const int* in_sizes, int n_in,
                              void* d_out, int out_size, void* d_ws, size_t ws_size,
                              hipStream_t stream) {
    const float* rij  = (const float*)d_in[0];
    const float* rcov = (const float*)d_in[1];
    const float* znum = (const float*)d_in[2];
    const int*   fa   = (const int*)d_in[3];
    const int*   sa   = (const int*)d_in[4];
    const int*   types= (const int*)d_in[5];
    float* out = (float*)d_out;
    int E = in_sizes[0];
    int nquad = E / 4;

    // d_out is poisoned 0xAA before every timed launch -> zero it ourselves.
    hipMemsetAsync(d_out, 0, (size_t)out_size * sizeof(float), stream);

    int blocks = (nquad + TPB * QPT - 1) / (TPB * QPT);
    if (blocks < 1) blocks = 1;
    zbl_kernel<<<blocks, TPB, 0, stream>>>(rij, rcov, znum, fa, sa, types, out, E, nquad);
}